// Round 4
// baseline (2244.592 us; speedup 1.0000x reference)
//
#include <hip/hip_runtime.h>

#define NN 100000
#define NE 1600000
#define HID 64
#define NL 3
#define BN_EPS 1e-5f
#define BSH 7
#define BNODES 128
#define NB 782                 // ceil(NN / BNODES)
#define BIN_CHUNK 16384
#define BIN_GRID ((NE + BIN_CHUNK - 1) / BIN_CHUNK)

__device__ __forceinline__ float bf2f(unsigned short u) {
    union { unsigned int i; float f; } v; v.i = ((unsigned int)u) << 16; return v.f;
}
__device__ __forceinline__ unsigned short f2bf(float f) {
    union { float f; unsigned int i; } v; v.f = f;
    unsigned int r = v.i + 0x7FFFu + ((v.i >> 16) & 1u);   // RNE
    return (unsigned short)(r >> 16);
}

// ---------------- input convert x f32 -> bf16 ----------------
__global__ void k_conv(const float* __restrict__ x, ushort* __restrict__ xb) {
    int i = blockIdx.x * blockDim.x + threadIdx.x;   // over NN*HID/4
    float4 v = ((const float4*)x)[i];
    ushort4 o;
    o.x = f2bf(v.x); o.y = f2bf(v.y); o.z = f2bf(v.z); o.w = f2bf(v.w);
    ((ushort4*)xb)[i] = o;
}

// ---------------- bucket histogram ----------------
__global__ void k_histB(const int* __restrict__ dst, int* __restrict__ ghist) {
    __shared__ int lh[NB];
    for (int i = threadIdx.x; i < NB; i += blockDim.x) lh[i] = 0;
    __syncthreads();
    int base = blockIdx.x * BIN_CHUNK;
    int end = min(base + BIN_CHUNK, NE);
    for (int e = base + threadIdx.x; e < end; e += blockDim.x)
        atomicAdd(&lh[dst[e] >> BSH], 1);
    __syncthreads();
    for (int i = threadIdx.x; i < NB; i += blockDim.x)
        if (lh[i]) atomicAdd(&ghist[i], lh[i]);
}

// ---------------- bucket scan (NB <= 1024, one block) ----------------
__global__ void k_scanB(const int* __restrict__ ghist, int* __restrict__ boff,
                        int* __restrict__ gcur) {
    __shared__ int t[1024];
    int tid = threadIdx.x;
    int v = (tid < NB) ? ghist[tid] : 0;
    t[tid] = v;
    __syncthreads();
    for (int d = 1; d < 1024; d <<= 1) {
        int u = (tid >= d) ? t[tid - d] : 0;
        __syncthreads();
        t[tid] += u;
        __syncthreads();
    }
    if (tid < NB) { int ex = t[tid] - v; boff[tid] = ex; gcur[tid] = ex; }
    if (tid == 0) boff[NB] = NE;
}

// ---------------- binning: block-local hist -> bulk reserve -> write ----------------
__global__ void k_binB(const int* __restrict__ ei, const float* __restrict__ att,
                       int* __restrict__ gcur, int2* __restrict__ evb) {
    __shared__ int lh[NB];
    for (int i = threadIdx.x; i < NB; i += blockDim.x) lh[i] = 0;
    __syncthreads();
    int base = blockIdx.x * BIN_CHUNK;
    int end = min(base + BIN_CHUNK, NE);
    for (int e = base + threadIdx.x; e < end; e += blockDim.x)
        atomicAdd(&lh[ei[NE + e] >> BSH], 1);
    __syncthreads();
    for (int i = threadIdx.x; i < NB; i += blockDim.x) {
        int c = lh[i];
        lh[i] = c ? atomicAdd(&gcur[i], c) : 0;   // lh becomes running cursor
    }
    __syncthreads();
    for (int e = base + threadIdx.x; e < end; e += blockDim.x) {
        int d = ei[NE + e];
        int b = d >> BSH;
        int p = atomicAdd(&lh[b], 1);
        evb[p] = make_int2(ei[e] | ((d & (BNODES - 1)) << 17), __float_as_int(att[e]));
    }
}

// ------- fused: bucket-local scatter-add in LDS (+x) -> Linear1 -> BN stats -------
__global__ __launch_bounds__(512, 4) void k_fused(const ushort* __restrict__ xb,
                                                  const int* __restrict__ boff,
                                                  const int2* __restrict__ evb,
                                                  const float* __restrict__ W1,
                                                  const float* __restrict__ b1,
                                                  ushort* __restrict__ hout,
                                                  float* __restrict__ stats) {
    __shared__ float acc[BNODES * HID];       // 32 KB: 128 node rows, f32
    __shared__ float red[16][HID];
    int tid = threadIdx.x;
    int wv = tid >> 6, c = tid & 63;
    int b = blockIdx.x;
    int node0 = b << BSH;
    int nvalid = min(BNODES, NN - node0);
    // phase 0: init accumulators with self rows (eps=0 -> coeff 1)
    for (int i = tid; i < nvalid * HID; i += 512)
        acc[i] = bf2f(xb[(size_t)node0 * HID + i]);
    __syncthreads();
    // phase 1: stream bucket edge list, scatter-add into LDS rows
    int e0 = boff[b], e1 = boff[b + 1];
    for (int tb = e0 + wv * 64; tb < e1; tb += 512) {
        int ee = tb + c;
        int ec = (ee < e1) ? ee : (e1 - 1);
        int2 t = evb[ec];                      // 64 edges staged lane-parallel
        if (ee >= e1) t.y = 0;                 // tail: att = 0
        int nj = e1 - tb; if (nj > 64) nj = 64;
        for (int j0 = 0; j0 < nj; j0 += 8) {
            float r[8]; float av[8]; int ad[8];
#pragma unroll
            for (int j = 0; j < 8; ++j) {
                int sp = __builtin_amdgcn_readlane(t.x, j0 + j);
                int ai = __builtin_amdgcn_readlane(t.y, j0 + j);
                av[j] = __int_as_float(ai);
                int src = sp & 0x1FFFF;
                ad[j] = (sp >> 17) * HID + c;
                r[j] = bf2f(xb[(size_t)src * HID + c]);   // scalar base + lane
            }
#pragma unroll
            for (int j = 0; j < 8; ++j)
                atomicAdd(&acc[ad[j]], r[j] * av[j]);     // ds_add_f32
        }
    }
    __syncthreads();
    // phase 2: Linear1 + BN stats straight from LDS
    float wr[HID];
#pragma unroll
    for (int k = 0; k < HID; ++k) wr[k] = W1[k * HID + c];
    float bl = b1[c];
    float s1 = 0.f, s2 = 0.f;
    for (int dl = wv; dl < nvalid; dl += 8) {
        const float4* rp = (const float4*)&acc[dl * HID];
        float o = bl;
#pragma unroll
        for (int k4 = 0; k4 < 16; ++k4) {
            float4 rv = rp[k4];
            o += rv.x * wr[4 * k4] + rv.y * wr[4 * k4 + 1]
               + rv.z * wr[4 * k4 + 2] + rv.w * wr[4 * k4 + 3];
        }
        hout[(size_t)(node0 + dl) * HID + c] = f2bf(o);
        s1 += o;
        s2 += o * o;
    }
    red[wv][c] = s1;
    red[8 + wv][c] = s2;
    __syncthreads();
    if (wv == 0) {
        float t1 = 0.f, t2 = 0.f;
#pragma unroll
        for (int w = 0; w < 8; ++w) { t1 += red[w][c]; t2 += red[8 + w][c]; }
        atomicAdd(&stats[c], t1);
        atomicAdd(&stats[HID + c], t2);
    }
}

// ------- mlp2: BN -> ReLU -> Linear2 -> ReLU; out bf16 (mid) or f32 (last) -------
__global__ __launch_bounds__(256, 4) void k_mlp2(const float* __restrict__ W2,
                                                 const float* __restrict__ b2,
                                                 const float* __restrict__ gamma,
                                                 const float* __restrict__ beta,
                                                 const float* __restrict__ stats,
                                                 const ushort* __restrict__ h,
                                                 ushort* __restrict__ xb_out,
                                                 float* __restrict__ f_out,
                                                 int write_f32) {
    __shared__ float rowlds[4][HID];
    int tid = threadIdx.x, wv = tid >> 6, c = tid & 63;
    float wr[HID];
#pragma unroll
    for (int k = 0; k < HID; ++k) wr[k] = W2[k * HID + c];
    float bl = b2[c];
    float mu = stats[c] * (1.0f / NN);
    float var = fmaxf(stats[HID + c] * (1.0f / NN) - mu * mu, 0.f);
    float aC = gamma[c] * rsqrtf(var + BN_EPS);
    float bC = beta[c] - mu * aC;
    int gw = blockIdx.x * 4 + wv, nw = gridDim.x * 4;
    for (int node = gw; node < NN; node += nw) {
        float v = bf2f(h[(size_t)node * HID + c]);
        v = fmaxf(aC * v + bC, 0.f);
        rowlds[wv][c] = v;
        float o = bl;
        const float4* rp = (const float4*)&rowlds[wv][0];
#pragma unroll
        for (int k4 = 0; k4 < 16; ++k4) {
            float4 rv = rp[k4];
            o += rv.x * wr[4 * k4] + rv.y * wr[4 * k4 + 1]
               + rv.z * wr[4 * k4 + 2] + rv.w * wr[4 * k4 + 3];
        }
        o = fmaxf(o, 0.f);
        if (write_f32) f_out[(size_t)node * HID + c] = o;
        else           xb_out[(size_t)node * HID + c] = f2bf(o);
    }
}

extern "C" void kernel_launch(void* const* d_in, const int* in_sizes, int n_in,
                              void* d_out, int out_size, void* d_ws, size_t ws_size,
                              hipStream_t stream) {
    const float* x_in  = (const float*)d_in[0];
    const int*   ei    = (const int*)d_in[1];
    const float* att   = (const float*)d_in[2];
    const float* W1    = (const float*)d_in[3];
    const float* b1    = (const float*)d_in[4];
    const float* gamma = (const float*)d_in[5];
    const float* beta  = (const float*)d_in[6];
    const float* W2    = (const float*)d_in[7];
    const float* b2    = (const float*)d_in[8];
    float* out = (float*)d_out;

    char* ws = (char*)d_ws;
    size_t off = 0;
    auto alloc = [&](size_t bytes) -> void* {
        void* p = ws + off;
        off += (bytes + 255) & ~(size_t)255;
        return p;
    };
    ushort* xb    = (ushort*)alloc((size_t)NN * HID * 2);
    ushort* hb    = (ushort*)alloc((size_t)NN * HID * 2);
    int*    ghist = (int*)alloc((size_t)NB * 4);
    int*    boff  = (int*)alloc((size_t)(NB + 1) * 4);
    int*    gcur  = (int*)alloc((size_t)NB * 4);
    int2*   evb   = (int2*)alloc((size_t)NE * 8);
    float*  stats = (float*)alloc(NL * 128 * 4);

    hipMemsetAsync(ghist, 0, (size_t)NB * 4, stream);
    hipMemsetAsync(stats, 0, NL * 128 * 4, stream);

    k_conv<<<(NN * HID / 4 + 255) / 256, 256, 0, stream>>>(x_in, xb);
    k_histB<<<BIN_GRID, 256, 0, stream>>>(ei + NE, ghist);
    k_scanB<<<1, 1024, 0, stream>>>(ghist, boff, gcur);
    k_binB<<<BIN_GRID, 256, 0, stream>>>(ei, att, gcur, evb);

    for (int l = 0; l < NL; ++l) {
        k_fused<<<NB, 512, 0, stream>>>(xb, boff, evb,
                                        W1 + (size_t)l * HID * HID, b1 + l * HID,
                                        hb, stats + l * 128);
        k_mlp2<<<1024, 256, 0, stream>>>(W2 + (size_t)l * HID * HID, b2 + l * HID,
                                         gamma + l * HID, beta + l * HID,
                                         stats + l * 128, hb,
                                         xb, out, (l == NL - 1) ? 1 : 0);
    }
}